// Round 13
// baseline (433.170 us; speedup 1.0000x reference)
//
#include <hip/hip_runtime.h>

constexpr int NGRAPH = 64;

// ---------------- concat x||pos -> h0 [N,16] ----------------
__global__ void concat_k(const float* __restrict__ x, const float* __restrict__ pos,
                         float* __restrict__ h0, int N) {
    int n = blockIdx.x * blockDim.x + threadIdx.x;
    if (n >= N) return;
    const float4* x4 = (const float4*)(x + (size_t)n * 8);
    const float4* p4 = (const float4*)(pos + (size_t)n * 8);
    float4* o4 = (float4*)(h0 + (size_t)n * 16);
    o4[0] = x4[0]; o4[1] = x4[1]; o4[2] = p4[0]; o4[3] = p4[1];
}

// ---------------- scan: block-local exclusive + block totals ----------------
__global__ void scan1_k(const int* __restrict__ deg, int* __restrict__ offs,
                        int* __restrict__ partials, int N) {
    __shared__ int sm[512];
    int t = threadIdx.x;
    int i = blockIdx.x * 512 + t;
    int v = (i < N) ? deg[i] : 0;
    sm[t] = v;
    __syncthreads();
    int acc = v;
    for (int d = 1; d < 512; d <<= 1) {
        int add = (t >= d) ? sm[t - d] : 0;
        __syncthreads();
        acc += add;
        sm[t] = acc;
        __syncthreads();
    }
    if (i < N) offs[i] = acc - v;
    if (t == 511) partials[blockIdx.x] = acc;
}

__global__ void scan2b_k(int* __restrict__ partials, int nb) {
    __shared__ int sm[512];
    int t = threadIdx.x;
    int v = (t < nb) ? partials[t] : 0;
    sm[t] = v;
    __syncthreads();
    int acc = v;
    for (int d = 1; d < 512; d <<= 1) {
        int add = (t >= d) ? sm[t - d] : 0;
        __syncthreads();
        acc += add;
        sm[t] = acc;
        __syncthreads();
    }
    if (t < nb) partials[t] = acc - v;
}

__global__ void scan3_k(int* __restrict__ offs, const int* __restrict__ partials,
                        int* __restrict__ cursor, int N, int E) {
    int i = blockIdx.x * 512 + threadIdx.x;
    if (i < N) {
        int o = offs[i] + partials[blockIdx.x];
        offs[i] = o;
        cursor[i] = o;
    }
    if (i == 0) offs[N] = E;
}

// ---------------- dinv ----------------
__global__ void dinv_k(const int* __restrict__ deg, float* __restrict__ dinv, int N) {
    int n = blockIdx.x * blockDim.x + threadIdx.x;
    if (n < N) dinv[n] = 1.0f / sqrtf((float)deg[n] + 1.0f);
}

// ---------------- bucket cursor init: bcur[b] = b * capB (fixed-capacity regions) ----------------
__global__ void binit_k(int* __restrict__ bcur, int nbuckets, int capB) {
    int t = threadIdx.x;
    if (t < 256) bcur[t] = (t < nbuckets) ? t * capB : 0;
}

// ---------------- bucket scatter: block-local counting sort of a 4096-edge chunk ----------------
__global__ __launch_bounds__(256) void scatter_k(
    const int* __restrict__ src, const int* __restrict__ dst,
    int* __restrict__ bcur, uint2* __restrict__ bucketed, int E, int shift)
{
    constexpr int CHUNK = 4096, EPT = 16;
    __shared__ uint2 recs[CHUNK];
    __shared__ int hist[256], sm[256], hoff[256], wcur[256], gbase[256];
    const int tid = threadIdx.x;
    const int base = blockIdx.x * CHUNK;
    int es[EPT], ed[EPT];
    hist[tid] = 0;
    __syncthreads();
#pragma unroll
    for (int k = 0; k < EPT; ++k) {
        int e = base + tid + k * 256;
        if (e < E) { es[k] = src[e]; ed[k] = dst[e]; }
        else       { ed[k] = -1; es[k] = 0; }
    }
#pragma unroll
    for (int k = 0; k < EPT; ++k)
        if (ed[k] >= 0) atomicAdd(&hist[ed[k] >> shift], 1);
    __syncthreads();
    int v = hist[tid];
    sm[tid] = v;
    __syncthreads();
    int acc = v;
    for (int d = 1; d < 256; d <<= 1) {
        int add = (tid >= d) ? sm[tid - d] : 0;
        __syncthreads();
        acc += add;
        sm[tid] = acc;
        __syncthreads();
    }
    hoff[tid] = acc - v;
    wcur[tid] = acc - v;
    __syncthreads();
#pragma unroll
    for (int k = 0; k < EPT; ++k) {
        if (ed[k] >= 0) {
            int b = ed[k] >> shift;
            int p = atomicAdd(&wcur[b], 1);
            recs[p] = make_uint2((unsigned)es[k], (unsigned)ed[k]);
        }
    }
    __syncthreads();
    int cnt = hist[tid];
    if (cnt > 0) gbase[tid] = atomicAdd(&bcur[tid], cnt);
    __syncthreads();
    const int VC = min(CHUNK, E - base);
    for (int i = tid; i < VC; i += 256) {
        uint2 r = recs[i];
        int b = (int)(r.y >> shift);
        bucketed[gbase[b] + (i - hoff[b])] = r;
    }
}

// ---------------- bucket degree count: LDS counters, coalesced deg write ----------------
__global__ __launch_bounds__(256) void bdeg_k(
    const uint2* __restrict__ bucketed, const int* __restrict__ bcur,
    int* __restrict__ deg, int capB, int N, int shift)
{
    __shared__ int lcnt[512];
    const int b = blockIdx.x;
    const int node_lo = b << shift;
    const int node_hi = min(node_lo + (1 << shift), N);
    const int range = node_hi - node_lo;
    const int tid = threadIdx.x;
    for (int i = tid; i < range; i += 256) lcnt[i] = 0;
    __syncthreads();
    const int beg = b * capB;
    const int end = bcur[b];
    for (int i = beg + tid; i < end; i += 256) {
        uint2 r = bucketed[i];
        atomicAdd(&lcnt[(int)r.y - node_lo], 1);
    }
    __syncthreads();
    for (int i = tid; i < range; i += 256) deg[node_lo + i] = lcnt[i];
}

// ---------------- bucket fill: csr window built in LDS, per-node src-sorted ----------------
// Sorting each node's segment by src turns the downstream gathers into a
// synchronized sweep over the h-table (sorted uniform = quantiles), shrinking
// the instantaneous working set to an L2/L3-resident window.
__global__ __launch_bounds__(256) void bfill_k(
    const uint2* __restrict__ bucketed, const int* __restrict__ bcur,
    const int* __restrict__ offs, int* __restrict__ gcur, int* __restrict__ csr,
    int capB, int N, int shift)
{
    __shared__ int lcsr[16384];
    __shared__ int lcur[512];
    const int b = blockIdx.x;
    const int node_lo = b << shift;
    const int node_hi = min(node_lo + (1 << shift), N);
    const int wbase = offs[node_lo];
    const int wend  = offs[node_hi];
    const int wsize = wend - wbase;
    const int range = node_hi - node_lo;
    const int beg = b * capB;
    const int end = bcur[b];
    const int tid = threadIdx.x;
    if (wsize <= 16384 && range <= 512) {
        for (int i = tid; i < range; i += 256)
            lcur[i] = offs[node_lo + i] - wbase;
        __syncthreads();
        for (int i = beg + tid; i < end; i += 256) {
            uint2 r = bucketed[i];
            int p = atomicAdd(&lcur[(int)r.y - node_lo], 1);
            lcsr[p] = (int)r.x;
        }
        __syncthreads();
        // per-node insertion sort by src (segments ~16 elems; 2 nodes/thread)
        for (int nn = tid; nn < range; nn += 256) {
            int s0 = (nn == 0) ? 0 : lcur[nn - 1];   // lcur[i] is now segment END
            int s1 = lcur[nn];
            for (int i = s0 + 1; i < s1; ++i) {
                int key = lcsr[i];
                int j = i - 1;
                while (j >= s0 && lcsr[j] > key) { lcsr[j + 1] = lcsr[j]; --j; }
                lcsr[j + 1] = key;
            }
        }
        __syncthreads();
        for (int i = tid; i < wsize; i += 256)
            csr[wbase + i] = lcsr[i];
    } else {
        for (int i = beg + tid; i < end; i += 256) {
            uint2 r = bucketed[i];
            int p = atomicAdd(&gcur[(int)r.y], 1);
            csr[p] = (int)r.x;
        }
    }
}

// ---------------- pure gather-aggregate ----------------
template <int K>
__global__ __launch_bounds__(256) void agg_k(
    const float* __restrict__ h, const int* __restrict__ offs, const int* __restrict__ csr,
    const float* __restrict__ dinv, float* __restrict__ g, int N)
{
    constexpr int GA = K / 4;
    int idx = blockIdx.x * 256 + threadIdx.x;
    int node = idx / GA;
    int lane = idx % GA;
    if (node >= N) return;
    const float4* __restrict__ h4 = (const float4*)h;
    int beg = offs[node], end = offs[node + 1];
    float4 a0 = {0.f, 0.f, 0.f, 0.f}, a1 = {0.f, 0.f, 0.f, 0.f};
    int j = beg;
    for (; j + 1 < end; j += 2) {
        int s0 = csr[j], s1 = csr[j + 1];
        float w0 = dinv[s0], w1 = dinv[s1];
        float4 v0 = h4[s0 * GA + lane];
        float4 v1 = h4[s1 * GA + lane];
        a0.x = fmaf(w0, v0.x, a0.x); a0.y = fmaf(w0, v0.y, a0.y);
        a0.z = fmaf(w0, v0.z, a0.z); a0.w = fmaf(w0, v0.w, a0.w);
        a1.x = fmaf(w1, v1.x, a1.x); a1.y = fmaf(w1, v1.y, a1.y);
        a1.z = fmaf(w1, v1.z, a1.z); a1.w = fmaf(w1, v1.w, a1.w);
    }
    if (j < end) {
        int s = csr[j];
        float w = dinv[s];
        float4 v = h4[s * GA + lane];
        a0.x = fmaf(w, v.x, a0.x); a0.y = fmaf(w, v.y, a0.y);
        a0.z = fmaf(w, v.z, a0.z); a0.w = fmaf(w, v.w, a0.w);
    }
    float dn = dinv[node], dn2 = dn * dn;
    float4 hs = h4[node * GA + lane];
    float4 o;
    o.x = fmaf(dn, a0.x + a1.x, dn2 * hs.x);
    o.y = fmaf(dn, a0.y + a1.y, dn2 * hs.y);
    o.z = fmaf(dn, a0.z + a1.z, dn2 * hs.z);
    o.w = fmaf(dn, a0.w + a1.w, dn2 * hs.w);
    ((float4*)g)[node * GA + lane] = o;
}

// ---------------- streaming gemm: out = [relu](g @ W + b) [then @ W4 if FUSE4] ----------------
template <int K, int OUT, bool RELU, bool FUSE4>
__global__ __launch_bounds__(256) void gemm_k(
    const float* __restrict__ g, const float* __restrict__ W, const float* __restrict__ bias,
    const float* __restrict__ W4, float* __restrict__ out, int N, int ntiles)
{
    constexpr int JG   = OUT / 4;
    constexpr int NTHN = 256 / JG;
    constexpr int NPB  = NTHN * 2;
    constexpr int ISTR = 132;

    __shared__ float Wl[K * OUT];
    __shared__ float bl[OUT];
    __shared__ float W4l[FUSE4 ? 1280 : 1];
    __shared__ float inter[FUSE4 ? NPB * ISTR : 1];

    const int tid = threadIdx.x;
    for (int i = tid; i < K * OUT; i += 256) Wl[i] = W[i];
    for (int i = tid; i < OUT; i += 256) bl[i] = bias[i];
    if constexpr (FUSE4)
        for (int i = tid; i < 1280; i += 256) W4l[i] = W4[i];
    __syncthreads();

    const int jg  = tid % JG;
    const int bnl = tid / JG;
    const float4 bfrag = *(const float4*)&bl[jg * 4];

    for (int tile = blockIdx.x; tile < ntiles; tile += gridDim.x) {
        const int base = tile * NPB;
        int n0 = base + bnl, n1 = base + bnl + NTHN;
        int n0c = n0 < N ? n0 : N - 1;
        int n1c = n1 < N ? n1 : N - 1;
        const float* r0 = g + (size_t)n0c * K;
        const float* r1 = g + (size_t)n1c * K;
        float4 a0 = bfrag, a1 = bfrag;
#pragma unroll
        for (int k = 0; k < K; k += 4) {
            float4 x0 = *(const float4*)&r0[k];
            float4 x1 = *(const float4*)&r1[k];
            float4 w0 = *(const float4*)&Wl[(k + 0) * OUT + jg * 4];
            float4 w1 = *(const float4*)&Wl[(k + 1) * OUT + jg * 4];
            float4 w2 = *(const float4*)&Wl[(k + 2) * OUT + jg * 4];
            float4 w3 = *(const float4*)&Wl[(k + 3) * OUT + jg * 4];
            a0.x = fmaf(x0.x, w0.x, a0.x); a0.y = fmaf(x0.x, w0.y, a0.y);
            a0.z = fmaf(x0.x, w0.z, a0.z); a0.w = fmaf(x0.x, w0.w, a0.w);
            a0.x = fmaf(x0.y, w1.x, a0.x); a0.y = fmaf(x0.y, w1.y, a0.y);
            a0.z = fmaf(x0.y, w1.z, a0.z); a0.w = fmaf(x0.y, w1.w, a0.w);
            a0.x = fmaf(x0.z, w2.x, a0.x); a0.y = fmaf(x0.z, w2.y, a0.y);
            a0.z = fmaf(x0.z, w2.z, a0.z); a0.w = fmaf(x0.z, w2.w, a0.w);
            a0.x = fmaf(x0.w, w3.x, a0.x); a0.y = fmaf(x0.w, w3.y, a0.y);
            a0.z = fmaf(x0.w, w3.z, a0.z); a0.w = fmaf(x0.w, w3.w, a0.w);
            a1.x = fmaf(x1.x, w0.x, a1.x); a1.y = fmaf(x1.x, w0.y, a1.y);
            a1.z = fmaf(x1.x, w0.z, a1.z); a1.w = fmaf(x1.x, w0.w, a1.w);
            a1.x = fmaf(x1.y, w1.x, a1.x); a1.y = fmaf(x1.y, w1.y, a1.y);
            a1.z = fmaf(x1.y, w1.z, a1.z); a1.w = fmaf(x1.y, w1.w, a1.w);
            a1.x = fmaf(x1.z, w2.x, a1.x); a1.y = fmaf(x1.z, w2.y, a1.y);
            a1.z = fmaf(x1.z, w2.z, a1.z); a1.w = fmaf(x1.z, w2.w, a1.w);
            a1.x = fmaf(x1.w, w3.x, a1.x); a1.y = fmaf(x1.w, w3.y, a1.y);
            a1.z = fmaf(x1.w, w3.z, a1.z); a1.w = fmaf(x1.w, w3.w, a1.w);
        }
        if (RELU) {
            a0.x = fmaxf(a0.x, 0.f); a0.y = fmaxf(a0.y, 0.f);
            a0.z = fmaxf(a0.z, 0.f); a0.w = fmaxf(a0.w, 0.f);
            a1.x = fmaxf(a1.x, 0.f); a1.y = fmaxf(a1.y, 0.f);
            a1.z = fmaxf(a1.z, 0.f); a1.w = fmaxf(a1.w, 0.f);
        }
        if constexpr (!FUSE4) {
            if (n0 < N) *(float4*)&out[(size_t)n0 * OUT + jg * 4] = a0;
            if (n1 < N) *(float4*)&out[(size_t)n1 * OUT + jg * 4] = a1;
        } else {
            *(float4*)&inter[bnl * ISTR + jg * 4] = a0;
            *(float4*)&inter[(bnl + NTHN) * ISTR + jg * 4] = a1;
            __syncthreads();
            int nl = tid >> 4, j = tid & 15;
            int gn = base + nl;
            if (j < 10 && gn < N) {
                const float* iv = &inter[nl * ISTR];
                float acc = 0.f;
#pragma unroll
                for (int k = 0; k < 128; k += 4) {
                    float4 v = *(const float4*)&iv[k];
                    acc = fmaf(v.x, W4l[(k + 0) * 10 + j], acc);
                    acc = fmaf(v.y, W4l[(k + 1) * 10 + j], acc);
                    acc = fmaf(v.z, W4l[(k + 2) * 10 + j], acc);
                    acc = fmaf(v.w, W4l[(k + 3) * 10 + j], acc);
                }
                out[(size_t)gn * 10 + j] = acc;
            }
            __syncthreads();
        }
    }
}

// ---------------- fused agg(10) + bias + per-graph mean pool partials ----------------
__global__ __launch_bounds__(256) void aggpool_k(
    const float* __restrict__ t, const int* __restrict__ offs, const int* __restrict__ csr,
    const float* __restrict__ dinv, const float* __restrict__ b4, const int* __restrict__ batch,
    float* __restrict__ pool, int N)
{
    __shared__ float lp[NGRAPH * 11];
    int tid = threadIdx.x;
    for (int i = tid; i < NGRAPH * 11; i += 256) lp[i] = 0.f;
    __syncthreads();
    int nl = tid / 10;
    int j = tid - nl * 10;
    int g = blockIdx.x * 25 + nl;
    if (nl < 25 && g < N) {
        int beg = offs[g], end = offs[g + 1];
        float acc0 = 0.f, acc1 = 0.f;
        int e = beg;
        for (; e + 1 < end; e += 2) {
            int s0 = csr[e], s1 = csr[e + 1];
            acc0 = fmaf(dinv[s0], t[s0 * 10 + j], acc0);
            acc1 = fmaf(dinv[s1], t[s1 * 10 + j], acc1);
        }
        if (e < end) {
            int s = csr[e];
            acc0 = fmaf(dinv[s], t[s * 10 + j], acc0);
        }
        float dn = dinv[g];
        float v = fmaf(dn, acc0 + acc1, dn * dn * t[g * 10 + j]) + b4[j];
        int gr = batch[g];
        atomicAdd(&lp[gr * 11 + j], v);
        if (j == 0) atomicAdd(&lp[gr * 11 + 10], 1.f);
    }
    __syncthreads();
    for (int i = tid; i < NGRAPH * 11; i += 256) {
        float v = lp[i];
        if (v != 0.f) atomicAdd(&pool[i], v);
    }
}

// ---------------- final divide ----------------
__global__ void final_k(const float* __restrict__ pool, float* __restrict__ out) {
    int i = blockIdx.x * blockDim.x + threadIdx.x;
    if (i >= NGRAPH * 10) return;
    int g = i / 10, f = i % 10;
    float c = pool[g * 11 + 10];
    out[i] = pool[g * 11 + f] / fmaxf(c, 1.f);
}

extern "C" void kernel_launch(void* const* d_in, const int* in_sizes, int n_in,
                              void* d_out, int out_size, void* d_ws, size_t ws_size,
                              hipStream_t stream) {
    const float* x   = (const float*)d_in[0];
    const float* pos = (const float*)d_in[1];
    const int* eidx  = (const int*)d_in[2];
    const int* batch = (const int*)d_in[3];
    const float* W1 = (const float*)d_in[4];  const float* b1 = (const float*)d_in[5];
    const float* W2 = (const float*)d_in[6];  const float* b2 = (const float*)d_in[7];
    const float* W3 = (const float*)d_in[8];  const float* b3 = (const float*)d_in[9];
    const float* W4 = (const float*)d_in[10]; const float* b4 = (const float*)d_in[11];

    const int N = in_sizes[0] / 8;
    const int E = in_sizes[2] / 2;
    const int* src = eidx;
    const int* dst = eidx + E;

    // bucket geometry (locality-structured: bucket = dst >> shift, <=256 buckets)
    int shift = 9;
    while ((((N + (1 << shift) - 1) >> shift)) > 256) ++shift;
    const int nbuckets = (N + (1 << shift) - 1) >> shift;
    const int capB = ((E / nbuckets) * 5) / 4 + 64;   // mean + ~23 sigma margin

    char* p = (char*)d_ws;
    auto alloc = [&](size_t bytes) { char* r = p; p += (bytes + 255) & ~255ull; return r; };
    int*   deg      = (int*)alloc((size_t)N * 4);
    int*   offs     = (int*)alloc((size_t)(N + 1) * 4);
    int*   cursor   = (int*)alloc((size_t)N * 4);
    int*   partials = (int*)alloc(512 * 4);
    int*   bcur     = (int*)alloc(256 * 4);
    float* dinv     = (float*)alloc((size_t)N * 4);
    int*   csr      = (int*)alloc((size_t)E * 4);
    uint2* bucketed = (uint2*)alloc(((size_t)nbuckets + 1) * capB * 8);  // +1 region padding
    float* bufX     = (float*)alloc((size_t)N * 64 * 4);
    float* bufY     = (float*)alloc((size_t)N * 64 * 4);
    float* bufZ     = (float*)alloc((size_t)N * 16 * 4);
    float* pool     = (float*)alloc(NGRAPH * 11 * 4);

    hipMemsetAsync(pool, 0, NGRAPH * 11 * 4, stream);

    concat_k<<<(N + 255) / 256, 256, 0, stream>>>(x, pos, bufZ, N);

    // CSR build: bucket-scatter -> LDS degree count -> scan -> LDS csr fill (+src-sort)
    binit_k<<<1, 256, 0, stream>>>(bcur, nbuckets, capB);
    scatter_k<<<(E + 4095) / 4096, 256, 0, stream>>>(src, dst, bcur, bucketed, E, shift);
    bdeg_k<<<nbuckets, 256, 0, stream>>>(bucketed, bcur, deg, capB, N, shift);

    const int nb = (N + 511) / 512;
    scan1_k<<<nb, 512, 0, stream>>>(deg, offs, partials, N);
    scan2b_k<<<1, 512, 0, stream>>>(partials, nb);
    scan3_k<<<nb, 512, 0, stream>>>(offs, partials, cursor, N, E);
    dinv_k<<<(N + 255) / 256, 256, 0, stream>>>(deg, dinv, N);
    bfill_k<<<nbuckets, 256, 0, stream>>>(bucketed, bcur, offs, cursor, csr, capB, N, shift);

    auto cap = [](int t) { return t < 2048 ? t : 2048; };

    // Layer 1: agg16 (Z->X), gemm 16->32 +relu (X->Y)
    agg_k<16><<<(N * 4 + 255) / 256, 256, 0, stream>>>(bufZ, offs, csr, dinv, bufX, N);
    {
        int nt = (N + 63) / 64;
        gemm_k<16, 32, true, false><<<cap(nt), 256, 0, stream>>>(bufX, W1, b1, nullptr, bufY, N, nt);
    }
    // Layer 2: agg32 (Y->X), gemm 32->64 +relu (X->Y)
    agg_k<32><<<(N * 8 + 255) / 256, 256, 0, stream>>>(bufY, offs, csr, dinv, bufX, N);
    {
        int nt = (N + 31) / 32;
        gemm_k<32, 64, true, false><<<cap(nt), 256, 0, stream>>>(bufX, W2, b2, nullptr, bufY, N, nt);
    }
    // Layer 3+4a: agg64 (Y->X), gemm 64->128 +relu, fused @W4 -> 10 (X->Z)
    agg_k<64><<<(N * 16 + 255) / 256, 256, 0, stream>>>(bufY, offs, csr, dinv, bufX, N);
    {
        int nt = (N + 15) / 16;
        gemm_k<64, 128, true, true><<<cap(nt), 256, 0, stream>>>(bufX, W3, b3, W4, bufZ, N, nt);
    }
    // Layer 4b: agg10 + b4 + pool partials (Z -> pool)
    aggpool_k<<<(N + 24) / 25, 256, 0, stream>>>(bufZ, offs, csr, dinv, b4, batch, pool, N);
    final_k<<<3, 256, 0, stream>>>(pool, (float*)d_out);
}

// Round 15
// 366.992 us; speedup vs baseline: 1.1803x; 1.1803x over previous
//
#include <hip/hip_runtime.h>

constexpr int NGRAPH = 64;

// ---------------- concat x||pos -> h0 [N,16] ----------------
__global__ void concat_k(const float* __restrict__ x, const float* __restrict__ pos,
                         float* __restrict__ h0, int N) {
    int n = blockIdx.x * blockDim.x + threadIdx.x;
    if (n >= N) return;
    const float4* x4 = (const float4*)(x + (size_t)n * 8);
    const float4* p4 = (const float4*)(pos + (size_t)n * 8);
    float4* o4 = (float4*)(h0 + (size_t)n * 16);
    o4[0] = x4[0]; o4[1] = x4[1]; o4[2] = p4[0]; o4[3] = p4[1];
}

// ---------------- scan: block-local exclusive + block totals ----------------
__global__ void scan1_k(const int* __restrict__ deg, int* __restrict__ offs,
                        int* __restrict__ partials, int N) {
    __shared__ int sm[512];
    int t = threadIdx.x;
    int i = blockIdx.x * 512 + t;
    int v = (i < N) ? deg[i] : 0;
    sm[t] = v;
    __syncthreads();
    int acc = v;
    for (int d = 1; d < 512; d <<= 1) {
        int add = (t >= d) ? sm[t - d] : 0;
        __syncthreads();
        acc += add;
        sm[t] = acc;
        __syncthreads();
    }
    if (i < N) offs[i] = acc - v;
    if (t == 511) partials[blockIdx.x] = acc;
}

__global__ void scan2b_k(int* __restrict__ partials, int nb) {
    __shared__ int sm[512];
    int t = threadIdx.x;
    int v = (t < nb) ? partials[t] : 0;
    sm[t] = v;
    __syncthreads();
    int acc = v;
    for (int d = 1; d < 512; d <<= 1) {
        int add = (t >= d) ? sm[t - d] : 0;
        __syncthreads();
        acc += add;
        sm[t] = acc;
        __syncthreads();
    }
    if (t < nb) partials[t] = acc - v;
}

__global__ void scan3_k(int* __restrict__ offs, const int* __restrict__ partials,
                        int* __restrict__ cursor, int N, int E) {
    int i = blockIdx.x * 512 + threadIdx.x;
    if (i < N) {
        int o = offs[i] + partials[blockIdx.x];
        offs[i] = o;
        cursor[i] = o;
    }
    if (i == 0) offs[N] = E;
}

// ---------------- dinv ----------------
__global__ void dinv_k(const int* __restrict__ deg, float* __restrict__ dinv, int N) {
    int n = blockIdx.x * blockDim.x + threadIdx.x;
    if (n < N) dinv[n] = 1.0f / sqrtf((float)deg[n] + 1.0f);
}

// ---------------- bucket cursor init: bcur[b] = b * capB (fixed-capacity regions) ----------------
__global__ void binit_k(int* __restrict__ bcur, int nbuckets, int capB) {
    int t = threadIdx.x;
    if (t < 256) bcur[t] = (t < nbuckets) ? t * capB : 0;
}

// ---------------- bucket scatter: block-local counting sort of a 4096-edge chunk ----------------
__global__ __launch_bounds__(256) void scatter_k(
    const int* __restrict__ src, const int* __restrict__ dst,
    int* __restrict__ bcur, uint2* __restrict__ bucketed, int E, int shift)
{
    constexpr int CHUNK = 4096, EPT = 16;
    __shared__ uint2 recs[CHUNK];
    __shared__ int hist[256], sm[256], hoff[256], wcur[256], gbase[256];
    const int tid = threadIdx.x;
    const int base = blockIdx.x * CHUNK;
    int es[EPT], ed[EPT];
    hist[tid] = 0;
    __syncthreads();
#pragma unroll
    for (int k = 0; k < EPT; ++k) {
        int e = base + tid + k * 256;
        if (e < E) { es[k] = src[e]; ed[k] = dst[e]; }
        else       { ed[k] = -1; es[k] = 0; }
    }
#pragma unroll
    for (int k = 0; k < EPT; ++k)
        if (ed[k] >= 0) atomicAdd(&hist[ed[k] >> shift], 1);
    __syncthreads();
    int v = hist[tid];
    sm[tid] = v;
    __syncthreads();
    int acc = v;
    for (int d = 1; d < 256; d <<= 1) {
        int add = (tid >= d) ? sm[tid - d] : 0;
        __syncthreads();
        acc += add;
        sm[tid] = acc;
        __syncthreads();
    }
    hoff[tid] = acc - v;
    wcur[tid] = acc - v;
    __syncthreads();
#pragma unroll
    for (int k = 0; k < EPT; ++k) {
        if (ed[k] >= 0) {
            int b = ed[k] >> shift;
            int p = atomicAdd(&wcur[b], 1);
            recs[p] = make_uint2((unsigned)es[k], (unsigned)ed[k]);
        }
    }
    __syncthreads();
    int cnt = hist[tid];
    if (cnt > 0) gbase[tid] = atomicAdd(&bcur[tid], cnt);
    __syncthreads();
    const int VC = min(CHUNK, E - base);
    for (int i = tid; i < VC; i += 256) {
        uint2 r = recs[i];
        int b = (int)(r.y >> shift);
        bucketed[gbase[b] + (i - hoff[b])] = r;
    }
}

// ---------------- bucket degree count: LDS counters, coalesced deg write ----------------
__global__ __launch_bounds__(256) void bdeg_k(
    const uint2* __restrict__ bucketed, const int* __restrict__ bcur,
    int* __restrict__ deg, int capB, int N, int shift)
{
    __shared__ int lcnt[512];
    const int b = blockIdx.x;
    const int node_lo = b << shift;
    const int node_hi = min(node_lo + (1 << shift), N);
    const int range = node_hi - node_lo;
    const int tid = threadIdx.x;
    for (int i = tid; i < range; i += 256) lcnt[i] = 0;
    __syncthreads();
    const int beg = b * capB;
    const int end = bcur[b];
    for (int i = beg + tid; i < end; i += 256) {
        uint2 r = bucketed[i];
        atomicAdd(&lcnt[(int)r.y - node_lo], 1);
    }
    __syncthreads();
    for (int i = tid; i < range; i += 256) deg[node_lo + i] = lcnt[i];
}

// ---------------- bucket fill: one block per bucket, csr window built in LDS (no sort) ----------------
__global__ __launch_bounds__(256) void bfill_k(
    const uint2* __restrict__ bucketed, const int* __restrict__ bcur,
    const int* __restrict__ offs, int* __restrict__ gcur, int* __restrict__ csr,
    int capB, int N, int shift)
{
    __shared__ int lcsr[16384];
    __shared__ int lcur[512];
    const int b = blockIdx.x;
    const int node_lo = b << shift;
    const int node_hi = min(node_lo + (1 << shift), N);
    const int wbase = offs[node_lo];
    const int wend  = offs[node_hi];
    const int wsize = wend - wbase;
    const int range = node_hi - node_lo;
    const int beg = b * capB;
    const int end = bcur[b];
    const int tid = threadIdx.x;
    if (wsize <= 16384 && range <= 512) {
        for (int i = tid; i < range; i += 256)
            lcur[i] = offs[node_lo + i] - wbase;
        __syncthreads();
        for (int i = beg + tid; i < end; i += 256) {
            uint2 r = bucketed[i];
            int p = atomicAdd(&lcur[(int)r.y - node_lo], 1);
            lcsr[p] = (int)r.x;
        }
        __syncthreads();
        for (int i = tid; i < wsize; i += 256)
            csr[wbase + i] = lcsr[i];
    } else {
        for (int i = beg + tid; i < end; i += 256) {
            uint2 r = bucketed[i];
            int p = atomicAdd(&gcur[(int)r.y], 1);
            csr[p] = (int)r.x;
        }
    }
}

// ---------------- pure gather-aggregate, 4-way edge ILP ----------------
template <int K>
__global__ __launch_bounds__(256) void agg_k(
    const float* __restrict__ h, const int* __restrict__ offs, const int* __restrict__ csr,
    const float* __restrict__ dinv, float* __restrict__ g, int N)
{
    constexpr int GA = K / 4;
    int idx = blockIdx.x * 256 + threadIdx.x;
    int node = idx / GA;
    int lane = idx % GA;
    if (node >= N) return;
    const float4* __restrict__ h4 = (const float4*)h;
    int beg = offs[node], end = offs[node + 1];
    float4 a0 = {0.f, 0.f, 0.f, 0.f}, a1 = {0.f, 0.f, 0.f, 0.f};
    float4 a2 = {0.f, 0.f, 0.f, 0.f}, a3 = {0.f, 0.f, 0.f, 0.f};
    int j = beg;
    for (; j + 3 < end; j += 4) {
        int s0 = csr[j], s1 = csr[j + 1], s2 = csr[j + 2], s3 = csr[j + 3];
        float w0 = dinv[s0], w1 = dinv[s1], w2 = dinv[s2], w3 = dinv[s3];
        float4 v0 = h4[s0 * GA + lane];
        float4 v1 = h4[s1 * GA + lane];
        float4 v2 = h4[s2 * GA + lane];
        float4 v3 = h4[s3 * GA + lane];
        a0.x = fmaf(w0, v0.x, a0.x); a0.y = fmaf(w0, v0.y, a0.y);
        a0.z = fmaf(w0, v0.z, a0.z); a0.w = fmaf(w0, v0.w, a0.w);
        a1.x = fmaf(w1, v1.x, a1.x); a1.y = fmaf(w1, v1.y, a1.y);
        a1.z = fmaf(w1, v1.z, a1.z); a1.w = fmaf(w1, v1.w, a1.w);
        a2.x = fmaf(w2, v2.x, a2.x); a2.y = fmaf(w2, v2.y, a2.y);
        a2.z = fmaf(w2, v2.z, a2.z); a2.w = fmaf(w2, v2.w, a2.w);
        a3.x = fmaf(w3, v3.x, a3.x); a3.y = fmaf(w3, v3.y, a3.y);
        a3.z = fmaf(w3, v3.z, a3.z); a3.w = fmaf(w3, v3.w, a3.w);
    }
    for (; j < end; ++j) {
        int s = csr[j];
        float w = dinv[s];
        float4 v = h4[s * GA + lane];
        a0.x = fmaf(w, v.x, a0.x); a0.y = fmaf(w, v.y, a0.y);
        a0.z = fmaf(w, v.z, a0.z); a0.w = fmaf(w, v.w, a0.w);
    }
    float dn = dinv[node], dn2 = dn * dn;
    float4 hs = h4[node * GA + lane];
    float sx = (a0.x + a1.x) + (a2.x + a3.x);
    float sy = (a0.y + a1.y) + (a2.y + a3.y);
    float sz = (a0.z + a1.z) + (a2.z + a3.z);
    float sw = (a0.w + a1.w) + (a2.w + a3.w);
    float4 o;
    o.x = fmaf(dn, sx, dn2 * hs.x);
    o.y = fmaf(dn, sy, dn2 * hs.y);
    o.z = fmaf(dn, sz, dn2 * hs.z);
    o.w = fmaf(dn, sw, dn2 * hs.w);
    ((float4*)g)[node * GA + lane] = o;
}

// ---------------- streaming gemm: out = [relu](g @ W + b) [then @ W4 if FUSE4] ----------------
template <int K, int OUT, bool RELU, bool FUSE4>
__global__ __launch_bounds__(256) void gemm_k(
    const float* __restrict__ g, const float* __restrict__ W, const float* __restrict__ bias,
    const float* __restrict__ W4, float* __restrict__ out, int N, int ntiles)
{
    constexpr int JG   = OUT / 4;
    constexpr int NTHN = 256 / JG;
    constexpr int NPB  = NTHN * 2;
    constexpr int ISTR = 132;

    __shared__ float Wl[K * OUT];
    __shared__ float bl[OUT];
    __shared__ float W4l[FUSE4 ? 1280 : 1];
    __shared__ float inter[FUSE4 ? NPB * ISTR : 1];

    const int tid = threadIdx.x;
    for (int i = tid; i < K * OUT; i += 256) Wl[i] = W[i];
    for (int i = tid; i < OUT; i += 256) bl[i] = bias[i];
    if constexpr (FUSE4)
        for (int i = tid; i < 1280; i += 256) W4l[i] = W4[i];
    __syncthreads();

    const int jg  = tid % JG;
    const int bnl = tid / JG;
    const float4 bfrag = *(const float4*)&bl[jg * 4];

    for (int tile = blockIdx.x; tile < ntiles; tile += gridDim.x) {
        const int base = tile * NPB;
        int n0 = base + bnl, n1 = base + bnl + NTHN;
        int n0c = n0 < N ? n0 : N - 1;
        int n1c = n1 < N ? n1 : N - 1;
        const float* r0 = g + (size_t)n0c * K;
        const float* r1 = g + (size_t)n1c * K;
        float4 a0 = bfrag, a1 = bfrag;
#pragma unroll
        for (int k = 0; k < K; k += 4) {
            float4 x0 = *(const float4*)&r0[k];
            float4 x1 = *(const float4*)&r1[k];
            float4 w0 = *(const float4*)&Wl[(k + 0) * OUT + jg * 4];
            float4 w1 = *(const float4*)&Wl[(k + 1) * OUT + jg * 4];
            float4 w2 = *(const float4*)&Wl[(k + 2) * OUT + jg * 4];
            float4 w3 = *(const float4*)&Wl[(k + 3) * OUT + jg * 4];
            a0.x = fmaf(x0.x, w0.x, a0.x); a0.y = fmaf(x0.x, w0.y, a0.y);
            a0.z = fmaf(x0.x, w0.z, a0.z); a0.w = fmaf(x0.x, w0.w, a0.w);
            a0.x = fmaf(x0.y, w1.x, a0.x); a0.y = fmaf(x0.y, w1.y, a0.y);
            a0.z = fmaf(x0.y, w1.z, a0.z); a0.w = fmaf(x0.y, w1.w, a0.w);
            a0.x = fmaf(x0.z, w2.x, a0.x); a0.y = fmaf(x0.z, w2.y, a0.y);
            a0.z = fmaf(x0.z, w2.z, a0.z); a0.w = fmaf(x0.z, w2.w, a0.w);
            a0.x = fmaf(x0.w, w3.x, a0.x); a0.y = fmaf(x0.w, w3.y, a0.y);
            a0.z = fmaf(x0.w, w3.z, a0.z); a0.w = fmaf(x0.w, w3.w, a0.w);
            a1.x = fmaf(x1.x, w0.x, a1.x); a1.y = fmaf(x1.x, w0.y, a1.y);
            a1.z = fmaf(x1.x, w0.z, a1.z); a1.w = fmaf(x1.x, w0.w, a1.w);
            a1.x = fmaf(x1.y, w1.x, a1.x); a1.y = fmaf(x1.y, w1.y, a1.y);
            a1.z = fmaf(x1.y, w1.z, a1.z); a1.w = fmaf(x1.y, w1.w, a1.w);
            a1.x = fmaf(x1.z, w2.x, a1.x); a1.y = fmaf(x1.z, w2.y, a1.y);
            a1.z = fmaf(x1.z, w2.z, a1.z); a1.w = fmaf(x1.z, w2.w, a1.w);
            a1.x = fmaf(x1.w, w3.x, a1.x); a1.y = fmaf(x1.w, w3.y, a1.y);
            a1.z = fmaf(x1.w, w3.z, a1.z); a1.w = fmaf(x1.w, w3.w, a1.w);
        }
        if (RELU) {
            a0.x = fmaxf(a0.x, 0.f); a0.y = fmaxf(a0.y, 0.f);
            a0.z = fmaxf(a0.z, 0.f); a0.w = fmaxf(a0.w, 0.f);
            a1.x = fmaxf(a1.x, 0.f); a1.y = fmaxf(a1.y, 0.f);
            a1.z = fmaxf(a1.z, 0.f); a1.w = fmaxf(a1.w, 0.f);
        }
        if constexpr (!FUSE4) {
            if (n0 < N) *(float4*)&out[(size_t)n0 * OUT + jg * 4] = a0;
            if (n1 < N) *(float4*)&out[(size_t)n1 * OUT + jg * 4] = a1;
        } else {
            *(float4*)&inter[bnl * ISTR + jg * 4] = a0;
            *(float4*)&inter[(bnl + NTHN) * ISTR + jg * 4] = a1;
            __syncthreads();
            int nl = tid >> 4, j = tid & 15;
            int gn = base + nl;
            if (j < 10 && gn < N) {
                const float* iv = &inter[nl * ISTR];
                float acc = 0.f;
#pragma unroll
                for (int k = 0; k < 128; k += 4) {
                    float4 v = *(const float4*)&iv[k];
                    acc = fmaf(v.x, W4l[(k + 0) * 10 + j], acc);
                    acc = fmaf(v.y, W4l[(k + 1) * 10 + j], acc);
                    acc = fmaf(v.z, W4l[(k + 2) * 10 + j], acc);
                    acc = fmaf(v.w, W4l[(k + 3) * 10 + j], acc);
                }
                out[(size_t)gn * 10 + j] = acc;
            }
            __syncthreads();
        }
    }
}

// ---------------- fused agg(10) + bias + per-graph mean pool partials ----------------
__global__ __launch_bounds__(256) void aggpool_k(
    const float* __restrict__ t, const int* __restrict__ offs, const int* __restrict__ csr,
    const float* __restrict__ dinv, const float* __restrict__ b4, const int* __restrict__ batch,
    float* __restrict__ pool, int N)
{
    __shared__ float lp[NGRAPH * 11];
    int tid = threadIdx.x;
    for (int i = tid; i < NGRAPH * 11; i += 256) lp[i] = 0.f;
    __syncthreads();
    int nl = tid / 10;
    int j = tid - nl * 10;
    int g = blockIdx.x * 25 + nl;
    if (nl < 25 && g < N) {
        int beg = offs[g], end = offs[g + 1];
        float acc0 = 0.f, acc1 = 0.f;
        int e = beg;
        for (; e + 1 < end; e += 2) {
            int s0 = csr[e], s1 = csr[e + 1];
            acc0 = fmaf(dinv[s0], t[s0 * 10 + j], acc0);
            acc1 = fmaf(dinv[s1], t[s1 * 10 + j], acc1);
        }
        if (e < end) {
            int s = csr[e];
            acc0 = fmaf(dinv[s], t[s * 10 + j], acc0);
        }
        float dn = dinv[g];
        float v = fmaf(dn, acc0 + acc1, dn * dn * t[g * 10 + j]) + b4[j];
        int gr = batch[g];
        atomicAdd(&lp[gr * 11 + j], v);
        if (j == 0) atomicAdd(&lp[gr * 11 + 10], 1.f);
    }
    __syncthreads();
    for (int i = tid; i < NGRAPH * 11; i += 256) {
        float v = lp[i];
        if (v != 0.f) atomicAdd(&pool[i], v);
    }
}

// ---------------- final divide ----------------
__global__ void final_k(const float* __restrict__ pool, float* __restrict__ out) {
    int i = blockIdx.x * blockDim.x + threadIdx.x;
    if (i >= NGRAPH * 10) return;
    int g = i / 10, f = i % 10;
    float c = pool[g * 11 + 10];
    out[i] = pool[g * 11 + f] / fmaxf(c, 1.f);
}

extern "C" void kernel_launch(void* const* d_in, const int* in_sizes, int n_in,
                              void* d_out, int out_size, void* d_ws, size_t ws_size,
                              hipStream_t stream) {
    const float* x   = (const float*)d_in[0];
    const float* pos = (const float*)d_in[1];
    const int* eidx  = (const int*)d_in[2];
    const int* batch = (const int*)d_in[3];
    const float* W1 = (const float*)d_in[4];  const float* b1 = (const float*)d_in[5];
    const float* W2 = (const float*)d_in[6];  const float* b2 = (const float*)d_in[7];
    const float* W3 = (const float*)d_in[8];  const float* b3 = (const float*)d_in[9];
    const float* W4 = (const float*)d_in[10]; const float* b4 = (const float*)d_in[11];

    const int N = in_sizes[0] / 8;
    const int E = in_sizes[2] / 2;
    const int* src = eidx;
    const int* dst = eidx + E;

    // bucket geometry (locality-structured: bucket = dst >> shift, <=256 buckets)
    int shift = 9;
    while ((((N + (1 << shift) - 1) >> shift)) > 256) ++shift;
    const int nbuckets = (N + (1 << shift) - 1) >> shift;
    const int capB = ((E / nbuckets) * 5) / 4 + 64;   // mean + ~23 sigma margin

    char* p = (char*)d_ws;
    auto alloc = [&](size_t bytes) { char* r = p; p += (bytes + 255) & ~255ull; return r; };
    int*   deg      = (int*)alloc((size_t)N * 4);
    int*   offs     = (int*)alloc((size_t)(N + 1) * 4);
    int*   cursor   = (int*)alloc((size_t)N * 4);
    int*   partials = (int*)alloc(512 * 4);
    int*   bcur     = (int*)alloc(256 * 4);
    float* dinv     = (float*)alloc((size_t)N * 4);
    int*   csr      = (int*)alloc((size_t)E * 4);
    uint2* bucketed = (uint2*)alloc(((size_t)nbuckets + 1) * capB * 8);  // +1 region padding
    float* bufX     = (float*)alloc((size_t)N * 64 * 4);
    float* bufY     = (float*)alloc((size_t)N * 64 * 4);
    float* bufZ     = (float*)alloc((size_t)N * 16 * 4);
    float* pool     = (float*)alloc(NGRAPH * 11 * 4);

    hipMemsetAsync(pool, 0, NGRAPH * 11 * 4, stream);

    concat_k<<<(N + 255) / 256, 256, 0, stream>>>(x, pos, bufZ, N);

    // CSR build: bucket-scatter -> LDS degree count -> scan -> LDS csr fill
    binit_k<<<1, 256, 0, stream>>>(bcur, nbuckets, capB);
    scatter_k<<<(E + 4095) / 4096, 256, 0, stream>>>(src, dst, bcur, bucketed, E, shift);
    bdeg_k<<<nbuckets, 256, 0, stream>>>(bucketed, bcur, deg, capB, N, shift);

    const int nb = (N + 511) / 512;
    scan1_k<<<nb, 512, 0, stream>>>(deg, offs, partials, N);
    scan2b_k<<<1, 512, 0, stream>>>(partials, nb);
    scan3_k<<<nb, 512, 0, stream>>>(offs, partials, cursor, N, E);
    dinv_k<<<(N + 255) / 256, 256, 0, stream>>>(deg, dinv, N);
    bfill_k<<<nbuckets, 256, 0, stream>>>(bucketed, bcur, offs, cursor, csr, capB, N, shift);

    auto cap = [](int t) { return t < 2048 ? t : 2048; };

    // Layer 1: agg16 (Z->X), gemm 16->32 +relu (X->Y)
    agg_k<16><<<(N * 4 + 255) / 256, 256, 0, stream>>>(bufZ, offs, csr, dinv, bufX, N);
    {
        int nt = (N + 63) / 64;
        gemm_k<16, 32, true, false><<<cap(nt), 256, 0, stream>>>(bufX, W1, b1, nullptr, bufY, N, nt);
    }
    // Layer 2: agg32 (Y->X), gemm 32->64 +relu (X->Y)
    agg_k<32><<<(N * 8 + 255) / 256, 256, 0, stream>>>(bufY, offs, csr, dinv, bufX, N);
    {
        int nt = (N + 31) / 32;
        gemm_k<32, 64, true, false><<<cap(nt), 256, 0, stream>>>(bufX, W2, b2, nullptr, bufY, N, nt);
    }
    // Layer 3+4a: agg64 (Y->X), gemm 64->128 +relu, fused @W4 -> 10 (X->Z)
    agg_k<64><<<(N * 16 + 255) / 256, 256, 0, stream>>>(bufY, offs, csr, dinv, bufX, N);
    {
        int nt = (N + 15) / 16;
        gemm_k<64, 128, true, true><<<cap(nt), 256, 0, stream>>>(bufX, W3, b3, W4, bufZ, N, nt);
    }
    // Layer 4b: agg10 + b4 + pool partials (Z -> pool)
    aggpool_k<<<(N + 24) / 25, 256, 0, stream>>>(bufZ, offs, csr, dinv, b4, batch, pool, N);
    final_k<<<3, 256, 0, stream>>>(pool, (float*)d_out);
}

// Round 17
// 339.969 us; speedup vs baseline: 1.2741x; 1.0795x over previous
//
#include <hip/hip_runtime.h>

constexpr int NGRAPH = 64;

__device__ inline float bf2f_lo(unsigned u) {
    union { unsigned i; float f; } c; c.i = u << 16; return c.f;
}
__device__ inline float bf2f_hi(unsigned u) {
    union { unsigned i; float f; } c; c.i = u & 0xFFFF0000u; return c.f;
}
__device__ inline unsigned short f2bf(float f) {
    union { float f; unsigned i; } c; c.f = f;
    unsigned r = c.i + 0x7FFFu + ((c.i >> 16) & 1u);
    return (unsigned short)(r >> 16);
}
__device__ inline unsigned pk2(float lo, float hi) {
    return (unsigned)f2bf(lo) | ((unsigned)f2bf(hi) << 16);
}

// ---------------- concat x||pos -> h0 bf16 [N,16] ----------------
__global__ void concat_k(const float* __restrict__ x, const float* __restrict__ pos,
                         unsigned short* __restrict__ h0, int N) {
    int n = blockIdx.x * blockDim.x + threadIdx.x;
    if (n >= N) return;
    const float4* x4 = (const float4*)(x + (size_t)n * 8);
    const float4* p4 = (const float4*)(pos + (size_t)n * 8);
    float4 a = x4[0], b = x4[1], c = p4[0], d = p4[1];
    uint4 o0 = { pk2(a.x, a.y), pk2(a.z, a.w), pk2(b.x, b.y), pk2(b.z, b.w) };
    uint4 o1 = { pk2(c.x, c.y), pk2(c.z, c.w), pk2(d.x, d.y), pk2(d.z, d.w) };
    ((uint4*)h0)[(size_t)n * 2]     = o0;
    ((uint4*)h0)[(size_t)n * 2 + 1] = o1;
}

// ---------------- scan: block-local exclusive + block totals ----------------
__global__ void scan1_k(const int* __restrict__ deg, int* __restrict__ offs,
                        int* __restrict__ partials, int N) {
    __shared__ int sm[512];
    int t = threadIdx.x;
    int i = blockIdx.x * 512 + t;
    int v = (i < N) ? deg[i] : 0;
    sm[t] = v;
    __syncthreads();
    int acc = v;
    for (int d = 1; d < 512; d <<= 1) {
        int add = (t >= d) ? sm[t - d] : 0;
        __syncthreads();
        acc += add;
        sm[t] = acc;
        __syncthreads();
    }
    if (i < N) offs[i] = acc - v;
    if (t == 511) partials[blockIdx.x] = acc;
}

__global__ void scan2b_k(int* __restrict__ partials, int nb) {
    __shared__ int sm[512];
    int t = threadIdx.x;
    int v = (t < nb) ? partials[t] : 0;
    sm[t] = v;
    __syncthreads();
    int acc = v;
    for (int d = 1; d < 512; d <<= 1) {
        int add = (t >= d) ? sm[t - d] : 0;
        __syncthreads();
        acc += add;
        sm[t] = acc;
        __syncthreads();
    }
    if (t < nb) partials[t] = acc - v;
}

__global__ void scan3_k(int* __restrict__ offs, const int* __restrict__ partials,
                        int* __restrict__ cursor, int N, int E) {
    int i = blockIdx.x * 512 + threadIdx.x;
    if (i < N) {
        int o = offs[i] + partials[blockIdx.x];
        offs[i] = o;
        cursor[i] = o;
    }
    if (i == 0) offs[N] = E;
}

// ---------------- dinv ----------------
__global__ void dinv_k(const int* __restrict__ deg, float* __restrict__ dinv, int N) {
    int n = blockIdx.x * blockDim.x + threadIdx.x;
    if (n < N) dinv[n] = 1.0f / sqrtf((float)deg[n] + 1.0f);
}

// ---------------- bucket cursor init ----------------
__global__ void binit_k(int* __restrict__ bcur, int nbuckets, int capB) {
    int t = threadIdx.x;
    if (t < 256) bcur[t] = (t < nbuckets) ? t * capB : 0;
}

// ---------------- bucket scatter ----------------
__global__ __launch_bounds__(256) void scatter_k(
    const int* __restrict__ src, const int* __restrict__ dst,
    int* __restrict__ bcur, uint2* __restrict__ bucketed, int E, int shift)
{
    constexpr int CHUNK = 4096, EPT = 16;
    __shared__ uint2 recs[CHUNK];
    __shared__ int hist[256], sm[256], hoff[256], wcur[256], gbase[256];
    const int tid = threadIdx.x;
    const int base = blockIdx.x * CHUNK;
    int es[EPT], ed[EPT];
    hist[tid] = 0;
    __syncthreads();
#pragma unroll
    for (int k = 0; k < EPT; ++k) {
        int e = base + tid + k * 256;
        if (e < E) { es[k] = src[e]; ed[k] = dst[e]; }
        else       { ed[k] = -1; es[k] = 0; }
    }
#pragma unroll
    for (int k = 0; k < EPT; ++k)
        if (ed[k] >= 0) atomicAdd(&hist[ed[k] >> shift], 1);
    __syncthreads();
    int v = hist[tid];
    sm[tid] = v;
    __syncthreads();
    int acc = v;
    for (int d = 1; d < 256; d <<= 1) {
        int add = (tid >= d) ? sm[tid - d] : 0;
        __syncthreads();
        acc += add;
        sm[tid] = acc;
        __syncthreads();
    }
    hoff[tid] = acc - v;
    wcur[tid] = acc - v;
    __syncthreads();
#pragma unroll
    for (int k = 0; k < EPT; ++k) {
        if (ed[k] >= 0) {
            int b = ed[k] >> shift;
            int p = atomicAdd(&wcur[b], 1);
            recs[p] = make_uint2((unsigned)es[k], (unsigned)ed[k]);
        }
    }
    __syncthreads();
    int cnt = hist[tid];
    if (cnt > 0) gbase[tid] = atomicAdd(&bcur[tid], cnt);
    __syncthreads();
    const int VC = min(CHUNK, E - base);
    for (int i = tid; i < VC; i += 256) {
        uint2 r = recs[i];
        int b = (int)(r.y >> shift);
        bucketed[gbase[b] + (i - hoff[b])] = r;
    }
}

// ---------------- bucket degree count ----------------
__global__ __launch_bounds__(256) void bdeg_k(
    const uint2* __restrict__ bucketed, const int* __restrict__ bcur,
    int* __restrict__ deg, int capB, int N, int shift)
{
    __shared__ int lcnt[512];
    const int b = blockIdx.x;
    const int node_lo = b << shift;
    const int node_hi = min(node_lo + (1 << shift), N);
    const int range = node_hi - node_lo;
    const int tid = threadIdx.x;
    for (int i = tid; i < range; i += 256) lcnt[i] = 0;
    __syncthreads();
    const int beg = b * capB;
    const int end = bcur[b];
    for (int i = beg + tid; i < end; i += 256) {
        uint2 r = bucketed[i];
        atomicAdd(&lcnt[(int)r.y - node_lo], 1);
    }
    __syncthreads();
    for (int i = tid; i < range; i += 256) deg[node_lo + i] = lcnt[i];
}

// ---------------- bucket fill ----------------
__global__ __launch_bounds__(256) void bfill_k(
    const uint2* __restrict__ bucketed, const int* __restrict__ bcur,
    const int* __restrict__ offs, int* __restrict__ gcur, int* __restrict__ csr,
    int capB, int N, int shift)
{
    __shared__ int lcsr[16384];
    __shared__ int lcur[512];
    const int b = blockIdx.x;
    const int node_lo = b << shift;
    const int node_hi = min(node_lo + (1 << shift), N);
    const int wbase = offs[node_lo];
    const int wend  = offs[node_hi];
    const int wsize = wend - wbase;
    const int range = node_hi - node_lo;
    const int beg = b * capB;
    const int end = bcur[b];
    const int tid = threadIdx.x;
    if (wsize <= 16384 && range <= 512) {
        for (int i = tid; i < range; i += 256)
            lcur[i] = offs[node_lo + i] - wbase;
        __syncthreads();
        for (int i = beg + tid; i < end; i += 256) {
            uint2 r = bucketed[i];
            int p = atomicAdd(&lcur[(int)r.y - node_lo], 1);
            lcsr[p] = (int)r.x;
        }
        __syncthreads();
        for (int i = tid; i < wsize; i += 256)
            csr[wbase + i] = lcsr[i];
    } else {
        for (int i = beg + tid; i < end; i += 256) {
            uint2 r = bucketed[i];
            int p = atomicAdd(&gcur[(int)r.y], 1);
            csr[p] = (int)r.x;
        }
    }
}

// ---------------- gather-aggregate from bf16 table -> f32 g ----------------
template <int K>
__global__ __launch_bounds__(256) void agg_k(
    const unsigned short* __restrict__ h, const int* __restrict__ offs,
    const int* __restrict__ csr, const float* __restrict__ dinv,
    float* __restrict__ g, int N)
{
    constexpr int GA = K / 4;
    int idx = blockIdx.x * 256 + threadIdx.x;
    int node = idx / GA;
    int lane = idx % GA;
    if (node >= N) return;
    const uint2* __restrict__ h2 = (const uint2*)h;
    int beg = offs[node], end = offs[node + 1];
    float4 a0 = {0.f, 0.f, 0.f, 0.f}, a1 = {0.f, 0.f, 0.f, 0.f};
    int j = beg;
    for (; j + 1 < end; j += 2) {
        int s0 = csr[j], s1 = csr[j + 1];
        float w0 = dinv[s0], w1 = dinv[s1];
        uint2 v0 = h2[(size_t)s0 * GA + lane];
        uint2 v1 = h2[(size_t)s1 * GA + lane];
        a0.x = fmaf(w0, bf2f_lo(v0.x), a0.x); a0.y = fmaf(w0, bf2f_hi(v0.x), a0.y);
        a0.z = fmaf(w0, bf2f_lo(v0.y), a0.z); a0.w = fmaf(w0, bf2f_hi(v0.y), a0.w);
        a1.x = fmaf(w1, bf2f_lo(v1.x), a1.x); a1.y = fmaf(w1, bf2f_hi(v1.x), a1.y);
        a1.z = fmaf(w1, bf2f_lo(v1.y), a1.z); a1.w = fmaf(w1, bf2f_hi(v1.y), a1.w);
    }
    if (j < end) {
        int s = csr[j];
        float w = dinv[s];
        uint2 v = h2[(size_t)s * GA + lane];
        a0.x = fmaf(w, bf2f_lo(v.x), a0.x); a0.y = fmaf(w, bf2f_hi(v.x), a0.y);
        a0.z = fmaf(w, bf2f_lo(v.y), a0.z); a0.w = fmaf(w, bf2f_hi(v.y), a0.w);
    }
    float dn = dinv[node], dn2 = dn * dn;
    uint2 hv = h2[(size_t)node * GA + lane];
    float4 o;
    o.x = fmaf(dn, a0.x + a1.x, dn2 * bf2f_lo(hv.x));
    o.y = fmaf(dn, a0.y + a1.y, dn2 * bf2f_hi(hv.x));
    o.z = fmaf(dn, a0.z + a1.z, dn2 * bf2f_lo(hv.y));
    o.w = fmaf(dn, a0.w + a1.w, dn2 * bf2f_hi(hv.y));
    ((float4*)g)[(size_t)node * GA + lane] = o;
}

// ---------------- streaming gemm: f32 in, bf16 out (t also bf16 when FUSE4) ----------------
template <int K, int OUT, bool RELU, bool FUSE4>
__global__ __launch_bounds__(256) void gemm_k(
    const float* __restrict__ g, const float* __restrict__ W, const float* __restrict__ bias,
    const float* __restrict__ W4, unsigned short* __restrict__ out, int N, int ntiles)
{
    constexpr int JG   = OUT / 4;
    constexpr int NTHN = 256 / JG;
    constexpr int NPB  = NTHN * 2;
    constexpr int ISTR = 132;

    __shared__ float Wl[K * OUT];
    __shared__ float bl[OUT];
    __shared__ float W4l[FUSE4 ? 1280 : 1];
    __shared__ float inter[FUSE4 ? NPB * ISTR : 1];

    const int tid = threadIdx.x;
    for (int i = tid; i < K * OUT; i += 256) Wl[i] = W[i];
    for (int i = tid; i < OUT; i += 256) bl[i] = bias[i];
    if constexpr (FUSE4)
        for (int i = tid; i < 1280; i += 256) W4l[i] = W4[i];
    __syncthreads();

    const int jg  = tid % JG;
    const int bnl = tid / JG;
    const float4 bfrag = *(const float4*)&bl[jg * 4];

    for (int tile = blockIdx.x; tile < ntiles; tile += gridDim.x) {
        const int base = tile * NPB;
        int n0 = base + bnl, n1 = base + bnl + NTHN;
        int n0c = n0 < N ? n0 : N - 1;
        int n1c = n1 < N ? n1 : N - 1;
        const float* r0 = g + (size_t)n0c * K;
        const float* r1 = g + (size_t)n1c * K;
        float4 a0 = bfrag, a1 = bfrag;
#pragma unroll
        for (int k = 0; k < K; k += 4) {
            float4 x0 = *(const float4*)&r0[k];
            float4 x1 = *(const float4*)&r1[k];
            float4 w0 = *(const float4*)&Wl[(k + 0) * OUT + jg * 4];
            float4 w1 = *(const float4*)&Wl[(k + 1) * OUT + jg * 4];
            float4 w2 = *(const float4*)&Wl[(k + 2) * OUT + jg * 4];
            float4 w3 = *(const float4*)&Wl[(k + 3) * OUT + jg * 4];
            a0.x = fmaf(x0.x, w0.x, a0.x); a0.y = fmaf(x0.x, w0.y, a0.y);
            a0.z = fmaf(x0.x, w0.z, a0.z); a0.w = fmaf(x0.x, w0.w, a0.w);
            a0.x = fmaf(x0.y, w1.x, a0.x); a0.y = fmaf(x0.y, w1.y, a0.y);
            a0.z = fmaf(x0.y, w1.z, a0.z); a0.w = fmaf(x0.y, w1.w, a0.w);
            a0.x = fmaf(x0.z, w2.x, a0.x); a0.y = fmaf(x0.z, w2.y, a0.y);
            a0.z = fmaf(x0.z, w2.z, a0.z); a0.w = fmaf(x0.z, w2.w, a0.w);
            a0.x = fmaf(x0.w, w3.x, a0.x); a0.y = fmaf(x0.w, w3.y, a0.y);
            a0.z = fmaf(x0.w, w3.z, a0.z); a0.w = fmaf(x0.w, w3.w, a0.w);
            a1.x = fmaf(x1.x, w0.x, a1.x); a1.y = fmaf(x1.x, w0.y, a1.y);
            a1.z = fmaf(x1.x, w0.z, a1.z); a1.w = fmaf(x1.x, w0.w, a1.w);
            a1.x = fmaf(x1.y, w1.x, a1.x); a1.y = fmaf(x1.y, w1.y, a1.y);
            a1.z = fmaf(x1.y, w1.z, a1.z); a1.w = fmaf(x1.y, w1.w, a1.w);
            a1.x = fmaf(x1.z, w2.x, a1.x); a1.y = fmaf(x1.z, w2.y, a1.y);
            a1.z = fmaf(x1.z, w2.z, a1.z); a1.w = fmaf(x1.z, w2.w, a1.w);
            a1.x = fmaf(x1.w, w3.x, a1.x); a1.y = fmaf(x1.w, w3.y, a1.y);
            a1.z = fmaf(x1.w, w3.z, a1.z); a1.w = fmaf(x1.w, w3.w, a1.w);
        }
        if (RELU) {
            a0.x = fmaxf(a0.x, 0.f); a0.y = fmaxf(a0.y, 0.f);
            a0.z = fmaxf(a0.z, 0.f); a0.w = fmaxf(a0.w, 0.f);
            a1.x = fmaxf(a1.x, 0.f); a1.y = fmaxf(a1.y, 0.f);
            a1.z = fmaxf(a1.z, 0.f); a1.w = fmaxf(a1.w, 0.f);
        }
        if constexpr (!FUSE4) {
            uint2 o0 = { pk2(a0.x, a0.y), pk2(a0.z, a0.w) };
            uint2 o1 = { pk2(a1.x, a1.y), pk2(a1.z, a1.w) };
            if (n0 < N) ((uint2*)out)[((size_t)n0 * OUT + jg * 4) / 4] = o0;
            if (n1 < N) ((uint2*)out)[((size_t)n1 * OUT + jg * 4) / 4] = o1;
        } else {
            *(float4*)&inter[bnl * ISTR + jg * 4] = a0;
            *(float4*)&inter[(bnl + NTHN) * ISTR + jg * 4] = a1;
            __syncthreads();
            int nl = tid >> 4, j = tid & 15;
            int gn = base + nl;
            if (j < 10 && gn < N) {
                const float* iv = &inter[nl * ISTR];
                float acc = 0.f;
#pragma unroll
                for (int k = 0; k < 128; k += 4) {
                    float4 v = *(const float4*)&iv[k];
                    acc = fmaf(v.x, W4l[(k + 0) * 10 + j], acc);
                    acc = fmaf(v.y, W4l[(k + 1) * 10 + j], acc);
                    acc = fmaf(v.z, W4l[(k + 2) * 10 + j], acc);
                    acc = fmaf(v.w, W4l[(k + 3) * 10 + j], acc);
                }
                out[(size_t)gn * 10 + j] = f2bf(acc);
            }
            __syncthreads();
        }
    }
}

// ---------------- fused agg(10, bf16 t) + bias + per-graph mean pool partials ----------------
__global__ __launch_bounds__(256) void aggpool_k(
    const unsigned short* __restrict__ t, const int* __restrict__ offs,
    const int* __restrict__ csr, const float* __restrict__ dinv,
    const float* __restrict__ b4, const int* __restrict__ batch,
    float* __restrict__ pool, int N)
{
    __shared__ float lp[NGRAPH * 11];
    int tid = threadIdx.x;
    for (int i = tid; i < NGRAPH * 11; i += 256) lp[i] = 0.f;
    __syncthreads();
    int nl = tid / 10;
    int j = tid - nl * 10;
    int g = blockIdx.x * 25 + nl;
    if (nl < 25 && g < N) {
        int beg = offs[g], end = offs[g + 1];
        float acc0 = 0.f, acc1 = 0.f;
        int e = beg;
        for (; e + 1 < end; e += 2) {
            int s0 = csr[e], s1 = csr[e + 1];
            acc0 = fmaf(dinv[s0], bf2f_lo((unsigned)t[(size_t)s0 * 10 + j]), acc0);
            acc1 = fmaf(dinv[s1], bf2f_lo((unsigned)t[(size_t)s1 * 10 + j]), acc1);
        }
        if (e < end) {
            int s = csr[e];
            acc0 = fmaf(dinv[s], bf2f_lo((unsigned)t[(size_t)s * 10 + j]), acc0);
        }
        float dn = dinv[g];
        float v = fmaf(dn, acc0 + acc1, dn * dn * bf2f_lo((unsigned)t[(size_t)g * 10 + j])) + b4[j];
        int gr = batch[g];
        atomicAdd(&lp[gr * 11 + j], v);
        if (j == 0) atomicAdd(&lp[gr * 11 + 10], 1.f);
    }
    __syncthreads();
    for (int i = tid; i < NGRAPH * 11; i += 256) {
        float v = lp[i];
        if (v != 0.f) atomicAdd(&pool[i], v);
    }
}

// ---------------- final divide ----------------
__global__ void final_k(const float* __restrict__ pool, float* __restrict__ out) {
    int i = blockIdx.x * blockDim.x + threadIdx.x;
    if (i >= NGRAPH * 10) return;
    int g = i / 10, f = i % 10;
    float c = pool[g * 11 + 10];
    out[i] = pool[g * 11 + f] / fmaxf(c, 1.f);
}

extern "C" void kernel_launch(void* const* d_in, const int* in_sizes, int n_in,
                              void* d_out, int out_size, void* d_ws, size_t ws_size,
                              hipStream_t stream) {
    const float* x   = (const float*)d_in[0];
    const float* pos = (const float*)d_in[1];
    const int* eidx  = (const int*)d_in[2];
    const int* batch = (const int*)d_in[3];
    const float* W1 = (const float*)d_in[4];  const float* b1 = (const float*)d_in[5];
    const float* W2 = (const float*)d_in[6];  const float* b2 = (const float*)d_in[7];
    const float* W3 = (const float*)d_in[8];  const float* b3 = (const float*)d_in[9];
    const float* W4 = (const float*)d_in[10]; const float* b4 = (const float*)d_in[11];

    const int N = in_sizes[0] / 8;
    const int E = in_sizes[2] / 2;
    const int* src = eidx;
    const int* dst = eidx + E;

    // bucket geometry (bucket = dst >> shift, <=256 buckets)
    int shift = 9;
    while ((((N + (1 << shift) - 1) >> shift)) > 256) ++shift;
    const int nbuckets = (N + (1 << shift) - 1) >> shift;
    const int capB = ((E / nbuckets) * 5) / 4 + 64;

    char* p = (char*)d_ws;
    auto alloc = [&](size_t bytes) { char* r = p; p += (bytes + 255) & ~255ull; return r; };
    int*   deg      = (int*)alloc((size_t)N * 4);
    int*   offs     = (int*)alloc((size_t)(N + 1) * 4);
    int*   cursor   = (int*)alloc((size_t)N * 4);
    int*   partials = (int*)alloc(512 * 4);
    int*   bcur     = (int*)alloc(256 * 4);
    float* dinv     = (float*)alloc((size_t)N * 4);
    int*   csr      = (int*)alloc((size_t)E * 4);
    uint2* bucketed = (uint2*)alloc(((size_t)nbuckets + 1) * capB * 8);
    float* bufX     = (float*)alloc((size_t)N * 64 * 4);              // f32 agg output
    unsigned short* hb = (unsigned short*)alloc((size_t)N * 64 * 2);  // bf16 h1/h2
    unsigned short* h0b = (unsigned short*)alloc((size_t)N * 16 * 2); // bf16 h0
    unsigned short* tb  = (unsigned short*)alloc((size_t)N * 10 * 2); // bf16 t
    float* pool     = (float*)alloc(NGRAPH * 11 * 4);

    hipMemsetAsync(pool, 0, NGRAPH * 11 * 4, stream);

    concat_k<<<(N + 255) / 256, 256, 0, stream>>>(x, pos, h0b, N);

    // CSR build: bucket-scatter -> LDS degree count -> scan -> LDS csr fill
    binit_k<<<1, 256, 0, stream>>>(bcur, nbuckets, capB);
    scatter_k<<<(E + 4095) / 4096, 256, 0, stream>>>(src, dst, bcur, bucketed, E, shift);
    bdeg_k<<<nbuckets, 256, 0, stream>>>(bucketed, bcur, deg, capB, N, shift);

    const int nb = (N + 511) / 512;
    scan1_k<<<nb, 512, 0, stream>>>(deg, offs, partials, N);
    scan2b_k<<<1, 512, 0, stream>>>(partials, nb);
    scan3_k<<<nb, 512, 0, stream>>>(offs, partials, cursor, N, E);
    dinv_k<<<(N + 255) / 256, 256, 0, stream>>>(deg, dinv, N);
    bfill_k<<<nbuckets, 256, 0, stream>>>(bucketed, bcur, offs, cursor, csr, capB, N, shift);

    auto cap = [](int t) { return t < 2048 ? t : 2048; };

    // Layer 1: agg16 (h0b->X f32), gemm 16->32 +relu (X->hb bf16)
    agg_k<16><<<(N * 4 + 255) / 256, 256, 0, stream>>>(h0b, offs, csr, dinv, bufX, N);
    {
        int nt = (N + 63) / 64;
        gemm_k<16, 32, true, false><<<cap(nt), 256, 0, stream>>>(bufX, W1, b1, nullptr, hb, N, nt);
    }
    // Layer 2: agg32 (hb->X), gemm 32->64 +relu (X->hb)
    agg_k<32><<<(N * 8 + 255) / 256, 256, 0, stream>>>(hb, offs, csr, dinv, bufX, N);
    {
        int nt = (N + 31) / 32;
        gemm_k<32, 64, true, false><<<cap(nt), 256, 0, stream>>>(bufX, W2, b2, nullptr, hb, N, nt);
    }
    // Layer 3+4a: agg64 (hb->X), gemm 64->128 +relu + @W4 -> tb bf16
    agg_k<64><<<(N * 16 + 255) / 256, 256, 0, stream>>>(hb, offs, csr, dinv, bufX, N);
    {
        int nt = (N + 15) / 16;
        gemm_k<64, 128, true, true><<<cap(nt), 256, 0, stream>>>(bufX, W3, b3, W4, tb, N, nt);
    }
    // Layer 4b: agg10 + b4 + pool partials
    aggpool_k<<<(N + 24) / 25, 256, 0, stream>>>(tb, offs, csr, dinv, b4, batch, pool, N);
    final_k<<<3, 256, 0, stream>>>(pool, (float*)d_out);
}